// Round 1
// baseline (323.524 us; speedup 1.0000x reference)
//
#include <hip/hip_runtime.h>

#define NG    2048
#define IMG_W 128
#define IMG_H 128
#define NPIX  (IMG_W * IMG_H)
#define CHUNK 128

// ---------------------------------------------------------------------------
// Kernel 1: per-gaussian preprocess (fp64 internally: radii's ceil() is a
// discontinuity; double keeps us on the same side of the boundary as the ref).
// Writes unsorted 10-float records [mx,my,A,B,C,op,z,r,g,b], the z sort key,
// and radii straight to its output slot (radii are in UNSORTED order).
// ---------------------------------------------------------------------------
__global__ __launch_bounds__(256) void preprocess_kernel(
    const float* __restrict__ means,
    const float* __restrict__ opac,
    const float* __restrict__ cols,
    const float* __restrict__ scales,
    const float* __restrict__ rots,
    const float* __restrict__ vm4,
    float* __restrict__ u,        // [NG][10] unsorted records
    float* __restrict__ zkey,     // [NG]
    float* __restrict__ radii_out)
{
    int i = blockIdx.x * blockDim.x + threadIdx.x;
    if (i >= NG) return;

    const double fx = 128.0, fy = 128.0;   // W/(2*tanfovx), H/(2*tanfovy)

    double R00 = vm4[0], R01 = vm4[1], R02 = vm4[2],  t0 = vm4[3];
    double R10 = vm4[4], R11 = vm4[5], R12 = vm4[6],  t1 = vm4[7];
    double R20 = vm4[8], R21 = vm4[9], R22 = vm4[10], t2 = vm4[11];

    double m0 = means[3*i+0], m1 = means[3*i+1], m2 = means[3*i+2];
    double x = R00*m0 + R01*m1 + R02*m2 + t0;
    double y = R10*m0 + R11*m1 + R12*m2 + t1;
    double z = R20*m0 + R21*m1 + R22*m2 + t2;

    double zc   = fmax(z, 1e-4);
    double invz = 1.0 / zc;
    const double limx = 1.3 * 0.5, limy = 1.3 * 0.5;
    double tx = fmin(limx, fmax(-limx, x * invz)) * zc;
    double ty = fmin(limy, fmax(-limy, y * invz)) * zc;

    double J00 = fx * invz, J02 = -fx * tx * invz * invz;
    double J11 = fy * invz, J12 = -fy * ty * invz * invz;

    double qw = rots[4*i+0], qx = rots[4*i+1], qy = rots[4*i+2], qz = rots[4*i+3];
    double qn = 1.0 / sqrt(qw*qw + qx*qx + qy*qy + qz*qz);
    qw *= qn; qx *= qn; qy *= qn; qz *= qn;

    double Rg00 = 1.0 - 2.0*(qy*qy + qz*qz), Rg01 = 2.0*(qx*qy - qw*qz), Rg02 = 2.0*(qx*qz + qw*qy);
    double Rg10 = 2.0*(qx*qy + qw*qz), Rg11 = 1.0 - 2.0*(qx*qx + qz*qz), Rg12 = 2.0*(qy*qz - qw*qx);
    double Rg20 = 2.0*(qx*qz - qw*qy), Rg21 = 2.0*(qy*qz + qw*qx), Rg22 = 1.0 - 2.0*(qx*qx + qy*qy);

    double s0 = scales[3*i+0], s1 = scales[3*i+1], s2 = scales[3*i+2]; // SCALE_MOD = 1
    double M00 = Rg00*s0, M01 = Rg01*s1, M02 = Rg02*s2;
    double M10 = Rg10*s0, M11 = Rg11*s1, M12 = Rg12*s2;
    double M20 = Rg20*s0, M21 = Rg21*s1, M22 = Rg22*s2;

    // Sigma = M M^T (symmetric)
    double S00 = M00*M00 + M01*M01 + M02*M02;
    double S01 = M00*M10 + M01*M11 + M02*M12;
    double S02 = M00*M20 + M01*M21 + M02*M22;
    double S11 = M10*M10 + M11*M11 + M12*M12;
    double S12 = M10*M20 + M11*M21 + M12*M22;
    double S22 = M20*M20 + M21*M21 + M22*M22;

    // T2 = J @ Rv  (J = [[J00,0,J02],[0,J11,J12]])
    double Ta0 = J00*R00 + J02*R20, Ta1 = J00*R01 + J02*R21, Ta2 = J00*R02 + J02*R22;
    double Tb0 = J11*R10 + J12*R20, Tb1 = J11*R11 + J12*R21, Tb2 = J11*R12 + J12*R22;

    // cov2d = T2 Sigma T2^T
    double Ua0 = Ta0*S00 + Ta1*S01 + Ta2*S02;
    double Ua1 = Ta0*S01 + Ta1*S11 + Ta2*S12;
    double Ua2 = Ta0*S02 + Ta1*S12 + Ta2*S22;
    double Ub0 = Tb0*S00 + Tb1*S01 + Tb2*S02;
    double Ub1 = Tb0*S01 + Tb1*S11 + Tb2*S12;
    double Ub2 = Tb0*S02 + Tb1*S12 + Tb2*S22;
    double cov00 = Ua0*Ta0 + Ua1*Ta1 + Ua2*Ta2;
    double cov01 = Ua0*Tb0 + Ua1*Tb1 + Ua2*Tb2;
    double cov11 = Ub0*Tb0 + Ub1*Tb1 + Ub2*Tb2;

    double a = cov00 + 0.3;
    double b = cov01;
    double c = cov11 + 0.3;
    double det = a*c - b*b;
    bool valid = (det > 0.0) && (z > 0.2);
    double inv_det = (det != 0.0) ? (1.0 / det) : 0.0;
    double conA =  c * inv_det;
    double conB = -b * inv_det;
    double conC =  a * inv_det;
    double mid = 0.5 * (a + c);
    double lam = mid + sqrt(fmax(mid*mid - det, 0.1));
    float radii = valid ? (float)ceil(3.0 * sqrt(lam)) : 0.0f;

    double mx = fx * (x * invz) + 0.5 * (IMG_W - 1);
    double my = fy * (y * invz) + 0.5 * (IMG_H - 1);

    float op = valid ? opac[i] : 0.0f;   // invalid => alpha forced to 0

    u[i*10 + 0] = (float)mx;
    u[i*10 + 1] = (float)my;
    u[i*10 + 2] = (float)conA;
    u[i*10 + 3] = (float)conB;
    u[i*10 + 4] = (float)conC;
    u[i*10 + 5] = op;
    u[i*10 + 6] = (float)z;
    u[i*10 + 7] = cols[3*i+0];
    u[i*10 + 8] = cols[3*i+1];
    u[i*10 + 9] = cols[3*i+2];
    zkey[i]     = (float)z;
    radii_out[i] = radii;
}

// ---------------------------------------------------------------------------
// Kernel 2: exact stable rank (== jnp.argsort semantics) + scatter to sorted
// SoA records. O(N^2) but N=2048: 4.2M LDS-broadcast compares.
// ---------------------------------------------------------------------------
__global__ __launch_bounds__(256) void rank_scatter_kernel(
    const float* __restrict__ u,
    const float* __restrict__ zkey,
    float* __restrict__ s)        // [NG][10] sorted records
{
    __shared__ float zl[NG];
    int tid = threadIdx.x;
    int i = blockIdx.x * 256 + tid;
    for (int j = tid; j < NG; j += 256) zl[j] = zkey[j];
    __syncthreads();

    float zi = zl[i];
    int rank = 0;
    #pragma unroll 8
    for (int j = 0; j < NG; ++j) {
        float zj = zl[j];
        rank += (zj < zi) || (zj == zi && j < i);
    }
    #pragma unroll
    for (int f = 0; f < 10; ++f) s[rank*10 + f] = u[i*10 + f];
}

// ---------------------------------------------------------------------------
// Kernel 3: per-pixel front-to-back compositing. One thread per pixel,
// gaussians staged through LDS in CHUNK-record blocks (broadcast reads).
// Running transmittance product == ref's exp(cumsum(log1p(-alpha))).
// ---------------------------------------------------------------------------
__global__ __launch_bounds__(64) void composite_kernel(
    const float* __restrict__ s,
    const float* __restrict__ bg,
    float* __restrict__ out)
{
    __shared__ float sg[CHUNK * 10];
    int p = blockIdx.x * 64 + threadIdx.x;
    float fpx = (float)(p & (IMG_W - 1));
    float fpy = (float)(p >> 7);

    float cr = 0.f, cg = 0.f, cb = 0.f, dep = 0.f, T = 1.f;

    for (int base = 0; base < NG; base += CHUNK) {
        __syncthreads();
        for (int k = threadIdx.x; k < CHUNK * 10; k += 64)
            sg[k] = s[base * 10 + k];
        __syncthreads();

        for (int g = 0; g < CHUNK; ++g) {
            float mx = sg[g*10 + 0];
            float my = sg[g*10 + 1];
            float A  = sg[g*10 + 2];
            float B  = sg[g*10 + 3];
            float C  = sg[g*10 + 4];
            float op = sg[g*10 + 5];
            float dx = mx - fpx;
            float dy = my - fpy;
            float power = -0.5f * (A*dx*dx + C*dy*dy) - B*dx*dy;
            if (power <= 0.0f) {
                float al = fminf(0.99f, op * __expf(power));
                if (al >= (1.0f / 255.0f)) {
                    float w = al * T;
                    dep += w * sg[g*10 + 6];
                    cr  += w * sg[g*10 + 7];
                    cg  += w * sg[g*10 + 8];
                    cb  += w * sg[g*10 + 9];
                    T *= (1.0f - al);
                }
            }
        }
    }

    out[0*NPIX + p] = cr + T * bg[0];
    out[1*NPIX + p] = cg + T * bg[1];
    out[2*NPIX + p] = cb + T * bg[2];
    out[3*NPIX + NG + p]        = dep;       // depth
    out[3*NPIX + NG + NPIX + p] = 1.f - T;   // alpha image
}

extern "C" void kernel_launch(void* const* d_in, const int* in_sizes, int n_in,
                              void* d_out, int out_size, void* d_ws, size_t ws_size,
                              hipStream_t stream)
{
    const float* means = (const float*)d_in[0];
    const float* opac  = (const float*)d_in[1];
    const float* cols  = (const float*)d_in[2];
    const float* scl   = (const float*)d_in[3];
    const float* rot   = (const float*)d_in[4];
    const float* vm    = (const float*)d_in[5];
    const float* bg    = (const float*)d_in[6];
    float* out = (float*)d_out;

    float* u    = (float*)d_ws;      // NG*10 floats (unsorted records)
    float* zkey = u + NG * 10;       // NG floats
    float* s    = zkey + NG;         // NG*10 floats (sorted records)

    preprocess_kernel<<<NG / 256, 256, 0, stream>>>(
        means, opac, cols, scl, rot, vm, u, zkey, out + 3 * NPIX);
    rank_scatter_kernel<<<NG / 256, 256, 0, stream>>>(u, zkey, s);
    composite_kernel<<<NPIX / 64, 64, 0, stream>>>(s, bg, out);
}

// Round 2
// 86.803 us; speedup vs baseline: 3.7271x; 3.7271x over previous
//
#include <hip/hip_runtime.h>

#define NG    2048
#define IMG_W 128
#define IMG_H 128
#define NPIX  (IMG_W * IMG_H)
#define REC   12            // padded record: mx,my,A,B,C,op,z,r,g,b,r2cull,pad

// ---------------------------------------------------------------------------
// Kernel 1: per-gaussian preprocess (fp64: radii's ceil() is a discontinuity).
// Record [mx,my,A,B,C,op,z,r,g,b,r2cull,0]. r2cull = conservative squared
// screen-distance beyond which alpha < 1/255 for sure:
//   alpha >= 1/255  =>  ||d||^2 <= 2*ln(255*op)*lam   (lam = λmax of cov2d)
// ---------------------------------------------------------------------------
__global__ __launch_bounds__(256) void preprocess_kernel(
    const float* __restrict__ means,
    const float* __restrict__ opac,
    const float* __restrict__ cols,
    const float* __restrict__ scales,
    const float* __restrict__ rots,
    const float* __restrict__ vm4,
    float* __restrict__ u,        // [NG][REC] unsorted records
    float* __restrict__ zkey,     // [NG]
    float* __restrict__ radii_out)
{
    int i = blockIdx.x * blockDim.x + threadIdx.x;
    if (i >= NG) return;

    const double fx = 128.0, fy = 128.0;   // W/(2*tanfovx), H/(2*tanfovy)

    double R00 = vm4[0], R01 = vm4[1], R02 = vm4[2],  t0 = vm4[3];
    double R10 = vm4[4], R11 = vm4[5], R12 = vm4[6],  t1 = vm4[7];
    double R20 = vm4[8], R21 = vm4[9], R22 = vm4[10], t2 = vm4[11];

    double m0 = means[3*i+0], m1 = means[3*i+1], m2 = means[3*i+2];
    double x = R00*m0 + R01*m1 + R02*m2 + t0;
    double y = R10*m0 + R11*m1 + R12*m2 + t1;
    double z = R20*m0 + R21*m1 + R22*m2 + t2;

    double zc   = fmax(z, 1e-4);
    double invz = 1.0 / zc;
    const double limx = 1.3 * 0.5, limy = 1.3 * 0.5;
    double tx = fmin(limx, fmax(-limx, x * invz)) * zc;
    double ty = fmin(limy, fmax(-limy, y * invz)) * zc;

    double J00 = fx * invz, J02 = -fx * tx * invz * invz;
    double J11 = fy * invz, J12 = -fy * ty * invz * invz;

    double qw = rots[4*i+0], qx = rots[4*i+1], qy = rots[4*i+2], qz = rots[4*i+3];
    double qn = 1.0 / sqrt(qw*qw + qx*qx + qy*qy + qz*qz);
    qw *= qn; qx *= qn; qy *= qn; qz *= qn;

    double Rg00 = 1.0 - 2.0*(qy*qy + qz*qz), Rg01 = 2.0*(qx*qy - qw*qz), Rg02 = 2.0*(qx*qz + qw*qy);
    double Rg10 = 2.0*(qx*qy + qw*qz), Rg11 = 1.0 - 2.0*(qx*qx + qz*qz), Rg12 = 2.0*(qy*qz - qw*qx);
    double Rg20 = 2.0*(qx*qz - qw*qy), Rg21 = 2.0*(qy*qz + qw*qx), Rg22 = 1.0 - 2.0*(qx*qx + qy*qy);

    double s0 = scales[3*i+0], s1 = scales[3*i+1], s2 = scales[3*i+2]; // SCALE_MOD = 1
    double M00 = Rg00*s0, M01 = Rg01*s1, M02 = Rg02*s2;
    double M10 = Rg10*s0, M11 = Rg11*s1, M12 = Rg12*s2;
    double M20 = Rg20*s0, M21 = Rg21*s1, M22 = Rg22*s2;

    double S00 = M00*M00 + M01*M01 + M02*M02;
    double S01 = M00*M10 + M01*M11 + M02*M12;
    double S02 = M00*M20 + M01*M21 + M02*M22;
    double S11 = M10*M10 + M11*M11 + M12*M12;
    double S12 = M10*M20 + M11*M21 + M12*M22;
    double S22 = M20*M20 + M21*M21 + M22*M22;

    double Ta0 = J00*R00 + J02*R20, Ta1 = J00*R01 + J02*R21, Ta2 = J00*R02 + J02*R22;
    double Tb0 = J11*R10 + J12*R20, Tb1 = J11*R11 + J12*R21, Tb2 = J11*R12 + J12*R22;

    double Ua0 = Ta0*S00 + Ta1*S01 + Ta2*S02;
    double Ua1 = Ta0*S01 + Ta1*S11 + Ta2*S12;
    double Ua2 = Ta0*S02 + Ta1*S12 + Ta2*S22;
    double Ub0 = Tb0*S00 + Tb1*S01 + Tb2*S02;
    double Ub1 = Tb0*S01 + Tb1*S11 + Tb2*S12;
    double Ub2 = Tb0*S02 + Tb1*S12 + Tb2*S22;
    double cov00 = Ua0*Ta0 + Ua1*Ta1 + Ua2*Ta2;
    double cov01 = Ua0*Tb0 + Ua1*Tb1 + Ua2*Tb2;
    double cov11 = Ub0*Tb0 + Ub1*Tb1 + Ub2*Tb2;

    double a = cov00 + 0.3;
    double b = cov01;
    double c = cov11 + 0.3;
    double det = a*c - b*b;
    bool valid = (det > 0.0) && (z > 0.2);
    double inv_det = (det != 0.0) ? (1.0 / det) : 0.0;
    double conA =  c * inv_det;
    double conB = -b * inv_det;
    double conC =  a * inv_det;
    double mid = 0.5 * (a + c);
    double lam = mid + sqrt(fmax(mid*mid - det, 0.1));
    float radii = valid ? (float)ceil(3.0 * sqrt(lam)) : 0.0f;

    double mx = fx * (x * invz) + 0.5 * (IMG_W - 1);
    double my = fy * (y * invz) + 0.5 * (IMG_H - 1);

    double op = valid ? (double)opac[i] : 0.0;

    // conservative cull radius^2 (margin covers all fp32 rounding downstream)
    double r2c = -1.0;
    if (op > 0.0) {
        double lnterm = log(255.0 * op);
        if (lnterm > 0.0) r2c = 2.0 * lnterm * lam * 1.0001 + 1e-3;
    }

    u[i*REC + 0]  = (float)mx;
    u[i*REC + 1]  = (float)my;
    u[i*REC + 2]  = (float)conA;
    u[i*REC + 3]  = (float)conB;
    u[i*REC + 4]  = (float)conC;
    u[i*REC + 5]  = (float)op;
    u[i*REC + 6]  = (float)z;
    u[i*REC + 7]  = cols[3*i+0];
    u[i*REC + 8]  = cols[3*i+1];
    u[i*REC + 9]  = cols[3*i+2];
    u[i*REC + 10] = (float)r2c;
    u[i*REC + 11] = 0.0f;
    zkey[i]       = (float)z;
    radii_out[i]  = radii;
}

// ---------------------------------------------------------------------------
// Kernel 2: exact stable rank (== jnp.argsort) + scatter to sorted records,
// plus a compact sorted (mx,my,r2cull) key array for the culling test.
// ---------------------------------------------------------------------------
__global__ __launch_bounds__(256) void rank_scatter_kernel(
    const float* __restrict__ u,
    const float* __restrict__ zkey,
    float* __restrict__ s,        // [NG][REC] sorted records
    float4* __restrict__ key4)    // [NG] sorted (mx,my,r2cull,0)
{
    __shared__ float zl[NG];
    int tid = threadIdx.x;
    int i = blockIdx.x * 256 + tid;
    for (int j = tid; j < NG; j += 256) zl[j] = zkey[j];
    __syncthreads();

    float zi = zl[i];
    int rank = 0;
    #pragma unroll 8
    for (int j = 0; j < NG; ++j) {
        float zj = zl[j];
        rank += (zj < zi) || (zj == zi && j < i);
    }
    const float4* src = (const float4*)(u + (size_t)i * REC);
    float4* dst = (float4*)(s + (size_t)rank * REC);
    float4 a0 = src[0], a1 = src[1], a2 = src[2];
    dst[0] = a0; dst[1] = a1; dst[2] = a2;
    key4[rank] = make_float4(a0.x, a0.y, a2.z, 0.0f);   // mx, my, r2cull
}

// ---------------------------------------------------------------------------
// Kernel 3: per-tile compositing with inline exact-conservative culling.
// One wave per 8x8 tile (256 tiles). Per 64-gaussian chunk: each lane tests
// one gaussian's cull disc against the tile rect, ballot-compacts passing
// records (order-preserving => sorted order kept) into LDS, then all 64
// pixel-lanes composite the compacted list via broadcast LDS reads.
// ---------------------------------------------------------------------------
__global__ __launch_bounds__(64) void composite_kernel(
    const float* __restrict__ s,
    const float4* __restrict__ key4,
    const float* __restrict__ bg,
    float* __restrict__ out)
{
    __shared__ float sg[64 * REC];

    int lane = threadIdx.x;
    int tile = blockIdx.x;
    int x0 = (tile & 15) * 8;
    int y0 = (tile >> 4) * 8;
    float x0f = (float)x0,      y0f = (float)y0;
    float x1f = (float)(x0 + 7), y1f = (float)(y0 + 7);

    int px = x0 + (lane & 7);
    int py = y0 + (lane >> 3);
    float fpx = (float)px, fpy = (float)py;
    int p = py * IMG_W + px;

    float cr = 0.f, cg = 0.f, cb = 0.f, dep = 0.f, T = 1.f;

    for (int base = 0; base < NG; base += 64) {
        int gi = base + lane;
        float4 k4 = key4[gi];
        float ddx = fmaxf(0.f, fmaxf(x0f - k4.x, k4.x - x1f));
        float ddy = fmaxf(0.f, fmaxf(y0f - k4.y, k4.y - y1f));
        bool pass = (ddx*ddx + ddy*ddy) <= k4.z;

        unsigned long long m = __ballot(pass);
        int ccnt = (int)__popcll(m);
        if (pass) {
            int slot = (int)__popcll(m & ((1ull << lane) - 1ull));
            const float4* r = (const float4*)(s + (size_t)gi * REC);
            float4 a0 = r[0], a1 = r[1], a2 = r[2];
            float4* dst = (float4*)(sg + slot * REC);
            dst[0] = a0; dst[1] = a1; dst[2] = a2;
        }
        __syncthreads();

        for (int g = 0; g < ccnt; ++g) {
            float mx = sg[g*REC + 0];
            float my = sg[g*REC + 1];
            float A  = sg[g*REC + 2];
            float B  = sg[g*REC + 3];
            float C  = sg[g*REC + 4];
            float op = sg[g*REC + 5];
            float dx = mx - fpx;
            float dy = my - fpy;
            float power = -0.5f * (A*dx*dx + C*dy*dy) - B*dx*dy;
            if (power <= 0.0f) {
                float al = fminf(0.99f, op * __expf(power));
                if (al >= (1.0f / 255.0f)) {
                    float w = al * T;
                    dep += w * sg[g*REC + 6];
                    cr  += w * sg[g*REC + 7];
                    cg  += w * sg[g*REC + 8];
                    cb  += w * sg[g*REC + 9];
                    T *= (1.0f - al);
                }
            }
        }
        __syncthreads();
    }

    out[0*NPIX + p] = cr + T * bg[0];
    out[1*NPIX + p] = cg + T * bg[1];
    out[2*NPIX + p] = cb + T * bg[2];
    out[3*NPIX + NG + p]        = dep;       // depth
    out[3*NPIX + NG + NPIX + p] = 1.f - T;   // alpha image
}

extern "C" void kernel_launch(void* const* d_in, const int* in_sizes, int n_in,
                              void* d_out, int out_size, void* d_ws, size_t ws_size,
                              hipStream_t stream)
{
    const float* means = (const float*)d_in[0];
    const float* opac  = (const float*)d_in[1];
    const float* cols  = (const float*)d_in[2];
    const float* scl   = (const float*)d_in[3];
    const float* rot   = (const float*)d_in[4];
    const float* vm    = (const float*)d_in[5];
    const float* bg    = (const float*)d_in[6];
    float* out = (float*)d_out;

    float*  u    = (float*)d_ws;          // NG*REC floats
    float*  zkey = u + NG * REC;          // NG floats
    float*  s    = zkey + NG;             // NG*REC floats (offset 16B-aligned)
    float4* key4 = (float4*)(s + NG * REC);

    preprocess_kernel<<<NG / 256, 256, 0, stream>>>(
        means, opac, cols, scl, rot, vm, u, zkey, out + 3 * NPIX);
    rank_scatter_kernel<<<NG / 256, 256, 0, stream>>>(u, zkey, s, key4);
    composite_kernel<<<NPIX / 64, 64, 0, stream>>>(s, key4, bg, out);
}

// Round 3
// 26.094 us; speedup vs baseline: 12.3984x; 3.3266x over previous
//
#include <hip/hip_runtime.h>

#define NG    2048
#define IMG_W 128
#define IMG_H 128
#define NPIX  (IMG_W * IMG_H)
#define REC   12            // record: mx,my,A,B,C,op,z,r,g,b,r2cull,pad

// ---------------------------------------------------------------------------
// Kernel 1: per-gaussian preprocess (fp64: radii's ceil() is a discontinuity).
// 64-thread blocks x 32 -> spread the latency-bound fp64 chain over 32 CUs.
// ---------------------------------------------------------------------------
__global__ __launch_bounds__(64) void preprocess_kernel(
    const float* __restrict__ means,
    const float* __restrict__ opac,
    const float* __restrict__ cols,
    const float* __restrict__ scales,
    const float* __restrict__ rots,
    const float* __restrict__ vm4,
    float* __restrict__ u,        // [NG][REC] unsorted records
    float* __restrict__ zkey,     // [NG]
    float* __restrict__ radii_out)
{
    int i = blockIdx.x * 64 + threadIdx.x;
    if (i >= NG) return;

    const double fx = 128.0, fy = 128.0;   // W/(2*tanfovx), H/(2*tanfovy)

    double R00 = vm4[0], R01 = vm4[1], R02 = vm4[2],  t0 = vm4[3];
    double R10 = vm4[4], R11 = vm4[5], R12 = vm4[6],  t1 = vm4[7];
    double R20 = vm4[8], R21 = vm4[9], R22 = vm4[10], t2 = vm4[11];

    double m0 = means[3*i+0], m1 = means[3*i+1], m2 = means[3*i+2];
    double x = R00*m0 + R01*m1 + R02*m2 + t0;
    double y = R10*m0 + R11*m1 + R12*m2 + t1;
    double z = R20*m0 + R21*m1 + R22*m2 + t2;

    double zc   = fmax(z, 1e-4);
    double invz = 1.0 / zc;
    const double limx = 1.3 * 0.5, limy = 1.3 * 0.5;
    double tx = fmin(limx, fmax(-limx, x * invz)) * zc;
    double ty = fmin(limy, fmax(-limy, y * invz)) * zc;

    double J00 = fx * invz, J02 = -fx * tx * invz * invz;
    double J11 = fy * invz, J12 = -fy * ty * invz * invz;

    double qw = rots[4*i+0], qx = rots[4*i+1], qy = rots[4*i+2], qz = rots[4*i+3];
    double qn = 1.0 / sqrt(qw*qw + qx*qx + qy*qy + qz*qz);
    qw *= qn; qx *= qn; qy *= qn; qz *= qn;

    double Rg00 = 1.0 - 2.0*(qy*qy + qz*qz), Rg01 = 2.0*(qx*qy - qw*qz), Rg02 = 2.0*(qx*qz + qw*qy);
    double Rg10 = 2.0*(qx*qy + qw*qz), Rg11 = 1.0 - 2.0*(qx*qx + qz*qz), Rg12 = 2.0*(qy*qz - qw*qx);
    double Rg20 = 2.0*(qx*qz - qw*qy), Rg21 = 2.0*(qy*qz + qw*qx), Rg22 = 1.0 - 2.0*(qx*qx + qy*qy);

    double s0 = scales[3*i+0], s1 = scales[3*i+1], s2 = scales[3*i+2]; // SCALE_MOD = 1
    double M00 = Rg00*s0, M01 = Rg01*s1, M02 = Rg02*s2;
    double M10 = Rg10*s0, M11 = Rg11*s1, M12 = Rg12*s2;
    double M20 = Rg20*s0, M21 = Rg21*s1, M22 = Rg22*s2;

    double S00 = M00*M00 + M01*M01 + M02*M02;
    double S01 = M00*M10 + M01*M11 + M02*M12;
    double S02 = M00*M20 + M01*M21 + M02*M22;
    double S11 = M10*M10 + M11*M11 + M12*M12;
    double S12 = M10*M20 + M11*M21 + M12*M22;
    double S22 = M20*M20 + M21*M21 + M22*M22;

    double Ta0 = J00*R00 + J02*R20, Ta1 = J00*R01 + J02*R21, Ta2 = J00*R02 + J02*R22;
    double Tb0 = J11*R10 + J12*R20, Tb1 = J11*R11 + J12*R21, Tb2 = J11*R12 + J12*R22;

    double Ua0 = Ta0*S00 + Ta1*S01 + Ta2*S02;
    double Ua1 = Ta0*S01 + Ta1*S11 + Ta2*S12;
    double Ua2 = Ta0*S02 + Ta1*S12 + Ta2*S22;
    double Ub0 = Tb0*S00 + Tb1*S01 + Tb2*S02;
    double Ub1 = Tb0*S01 + Tb1*S11 + Tb2*S12;
    double Ub2 = Tb0*S02 + Tb1*S12 + Tb2*S22;
    double cov00 = Ua0*Ta0 + Ua1*Ta1 + Ua2*Ta2;
    double cov01 = Ua0*Tb0 + Ua1*Tb1 + Ua2*Tb2;
    double cov11 = Ub0*Tb0 + Ub1*Tb1 + Ub2*Tb2;

    double a = cov00 + 0.3;
    double b = cov01;
    double c = cov11 + 0.3;
    double det = a*c - b*b;
    bool valid = (det > 0.0) && (z > 0.2);
    double inv_det = (det != 0.0) ? (1.0 / det) : 0.0;
    double conA =  c * inv_det;
    double conB = -b * inv_det;
    double conC =  a * inv_det;
    double mid = 0.5 * (a + c);
    double lam = mid + sqrt(fmax(mid*mid - det, 0.1));
    float radii = valid ? (float)ceil(3.0 * sqrt(lam)) : 0.0f;

    double mx = fx * (x * invz) + 0.5 * (IMG_W - 1);
    double my = fy * (y * invz) + 0.5 * (IMG_H - 1);

    double op = valid ? (double)opac[i] : 0.0;

    // conservative cull radius^2: alpha>=1/255 => ||d||^2 <= 2*ln(255*op)*lam
    double r2c = -1.0;
    if (op > 0.0) {
        double lnterm = log(255.0 * op);
        if (lnterm > 0.0) r2c = 2.0 * lnterm * lam * 1.0001 + 1e-3;
    }

    u[i*REC + 0]  = (float)mx;
    u[i*REC + 1]  = (float)my;
    u[i*REC + 2]  = (float)conA;
    u[i*REC + 3]  = (float)conB;
    u[i*REC + 4]  = (float)conC;
    u[i*REC + 5]  = (float)op;
    u[i*REC + 6]  = (float)z;
    u[i*REC + 7]  = cols[3*i+0];
    u[i*REC + 8]  = cols[3*i+1];
    u[i*REC + 9]  = cols[3*i+2];
    u[i*REC + 10] = (float)r2c;
    u[i*REC + 11] = 0.0f;
    zkey[i]       = (float)z;
    radii_out[i]  = radii;
}

// ---------------------------------------------------------------------------
// Kernel 2: exact stable rank (== jnp.argsort) + scatter. 16 lanes cooperate
// per gaussian (each scans 128 j's as 32 interleaved float4 LDS reads ->
// <=2-way bank aliasing), shfl_down tree-reduce within the 16-lane group.
// 128 blocks x 256 threads. Rank is a commutative sum -> partitioning exact.
// ---------------------------------------------------------------------------
__global__ __launch_bounds__(256) void rank_scatter_kernel(
    const float* __restrict__ u,
    const float* __restrict__ zkey,
    float* __restrict__ s,        // [NG][REC] sorted records
    float4* __restrict__ key4)    // [NG] sorted (mx,my,r2cull,0)
{
    __shared__ float zl[NG];
    int tid = threadIdx.x;
    for (int j = tid; j < NG; j += 256) zl[j] = zkey[j];
    __syncthreads();

    int g = tid >> 4;                 // gaussian-in-block 0..15
    int p = tid & 15;                 // part 0..15
    int i = blockIdx.x * 16 + g;
    float zi = zl[i];

    const float4* z4 = (const float4*)zl;
    int rank = 0;
    #pragma unroll 4
    for (int it = 0; it < 32; ++it) {
        int idx = it * 16 + p;        // interleaved float4 index
        float4 f = z4[idx];
        int j0 = idx * 4;
        rank += (f.x < zi) || (f.x == zi && (j0 + 0) < i);
        rank += (f.y < zi) || (f.y == zi && (j0 + 1) < i);
        rank += (f.z < zi) || (f.z == zi && (j0 + 2) < i);
        rank += (f.w < zi) || (f.w == zi && (j0 + 3) < i);
    }
    rank += __shfl_down(rank, 8, 16);
    rank += __shfl_down(rank, 4, 16);
    rank += __shfl_down(rank, 2, 16);
    rank += __shfl_down(rank, 1, 16);

    if (p == 0) {
        const float4* src = (const float4*)(u + (size_t)i * REC);
        float4 a0 = src[0], a1 = src[1], a2 = src[2];
        float4* dst = (float4*)(s + (size_t)rank * REC);
        dst[0] = a0; dst[1] = a1; dst[2] = a2;
        key4[rank] = make_float4(a0.x, a0.y, a2.z, 0.0f);   // mx, my, r2cull
    }
}

// ---------------------------------------------------------------------------
// Kernel 3: per-tile compositing, 4 waves/tile. Wave w composites depth
// segment [w*512,(w+1)*512) with local transmittance; ballot-cull per
// 64-chunk, records broadcast lane->wave via __shfl (shfls are uniform:
// executed by all lanes, sources are register values of passing lanes).
// Segments combined exactly: color = sum_w c_w * prod_{w'<w} T_w'.
// ---------------------------------------------------------------------------
__global__ __launch_bounds__(256) void composite_kernel(
    const float* __restrict__ s,
    const float4* __restrict__ key4,
    const float* __restrict__ bg,
    float* __restrict__ out)
{
    __shared__ float comb[4 * 64 * 5];   // stride 5 -> gcd(5,32)=1, no conflicts

    int tid  = threadIdx.x;
    int lane = tid & 63;
    int w    = tid >> 6;                 // segment/wave id 0..3
    int tile = blockIdx.x;
    int x0 = (tile & 15) * 8;
    int y0 = (tile >> 4) * 8;
    float x0f = (float)x0,       y0f = (float)y0;
    float x1f = (float)(x0 + 7), y1f = (float)(y0 + 7);

    int px = x0 + (lane & 7);
    int py = y0 + (lane >> 3);
    float fpx = (float)px, fpy = (float)py;
    int p = py * IMG_W + px;

    float cr = 0.f, cg = 0.f, cb = 0.f, dep = 0.f, T = 1.f;

    const int SEG = NG / 4;
    int segbase = w * SEG;
    for (int c = 0; c < SEG; c += 64) {
        int gi = segbase + c + lane;
        float4 k4 = key4[gi];
        float ddx = fmaxf(0.f, fmaxf(x0f - k4.x, k4.x - x1f));
        float ddy = fmaxf(0.f, fmaxf(y0f - k4.y, k4.y - y1f));
        bool pass = (ddx*ddx + ddy*ddy) <= k4.z;

        unsigned long long m = __ballot(pass);
        float4 a0 = make_float4(0.f,0.f,0.f,0.f);
        float4 a1 = a0;
        float2 a2 = make_float2(0.f,0.f);
        if (pass) {
            const float* r = s + (size_t)gi * REC;
            a0 = *(const float4*)(r);
            a1 = *(const float4*)(r + 4);
            a2 = *(const float2*)(r + 8);
        }
        while (m) {
            int b = __ffsll(m) - 1;      // lowest set bit = nearest depth
            m &= m - 1;
            float mx = __shfl(a0.x, b);
            float my = __shfl(a0.y, b);
            float A  = __shfl(a0.z, b);
            float B  = __shfl(a0.w, b);
            float C  = __shfl(a1.x, b);
            float op = __shfl(a1.y, b);
            float gz = __shfl(a1.z, b);
            float gr = __shfl(a1.w, b);
            float gg = __shfl(a2.x, b);
            float gb = __shfl(a2.y, b);
            float dx = mx - fpx;
            float dy = my - fpy;
            float power = -0.5f * (A*dx*dx + C*dy*dy) - B*dx*dy;
            if (power <= 0.0f) {
                float al = fminf(0.99f, op * __expf(power));
                if (al >= (1.0f / 255.0f)) {
                    float wg = al * T;
                    dep += wg * gz;
                    cr  += wg * gr;
                    cg  += wg * gg;
                    cb  += wg * gb;
                    T *= (1.0f - al);
                }
            }
        }
    }

    int cb_base = (w * 64 + lane) * 5;
    comb[cb_base + 0] = cr;
    comb[cb_base + 1] = cg;
    comb[cb_base + 2] = cb;
    comb[cb_base + 3] = dep;
    comb[cb_base + 4] = T;
    __syncthreads();

    if (w == 0) {
        float CR = 0.f, CG = 0.f, CB = 0.f, DEP = 0.f, TT = 1.f;
        #pragma unroll
        for (int ww = 0; ww < 4; ++ww) {
            int b2 = (ww * 64 + lane) * 5;
            CR  += TT * comb[b2 + 0];
            CG  += TT * comb[b2 + 1];
            CB  += TT * comb[b2 + 2];
            DEP += TT * comb[b2 + 3];
            TT  *= comb[b2 + 4];
        }
        out[0*NPIX + p] = CR + TT * bg[0];
        out[1*NPIX + p] = CG + TT * bg[1];
        out[2*NPIX + p] = CB + TT * bg[2];
        out[3*NPIX + NG + p]        = DEP;        // depth
        out[3*NPIX + NG + NPIX + p] = 1.f - TT;   // alpha image
    }
}

extern "C" void kernel_launch(void* const* d_in, const int* in_sizes, int n_in,
                              void* d_out, int out_size, void* d_ws, size_t ws_size,
                              hipStream_t stream)
{
    const float* means = (const float*)d_in[0];
    const float* opac  = (const float*)d_in[1];
    const float* cols  = (const float*)d_in[2];
    const float* scl   = (const float*)d_in[3];
    const float* rot   = (const float*)d_in[4];
    const float* vm    = (const float*)d_in[5];
    const float* bg    = (const float*)d_in[6];
    float* out = (float*)d_out;

    float*  u    = (float*)d_ws;          // NG*REC floats
    float*  zkey = u + NG * REC;          // NG floats
    float*  s    = zkey + NG;             // NG*REC floats (16B-aligned offset)
    float4* key4 = (float4*)(s + NG * REC);

    preprocess_kernel<<<NG / 64, 64, 0, stream>>>(
        means, opac, cols, scl, rot, vm, u, zkey, out + 3 * NPIX);
    rank_scatter_kernel<<<NG / 16, 256, 0, stream>>>(u, zkey, s, key4);
    composite_kernel<<<NPIX / 64, 256, 0, stream>>>(s, key4, bg, out);
}

// Round 4
// 23.221 us; speedup vs baseline: 13.9324x; 1.1237x over previous
//
#include <hip/hip_runtime.h>

#define NG    2048
#define IMG_W 128
#define IMG_H 128
#define NPIX  (IMG_W * IMG_H)
#define REC   12            // record: mx,my,A,B,C,op,z,r,g,b,r2cull,pad

// ---------------------------------------------------------------------------
// Kernel A: fused preprocess + exact stable rank + scatter.
// Phase 1: every block redundantly computes all 2048 z-keys (3 fp64 FMAs each)
//          into LDS -- deterministic, bit-identical across blocks.
// Phase 2: 16 lanes per gaussian scan the 2048 keys (interleaved float4 LDS
//          reads, broadcast + 2-way aliasing = conflict-free), shfl-reduce.
// Phase 3: lane p==0 runs the full fp64 preprocess (radii's ceil() is a
//          discontinuity -> fp64) and scatters the record to sorted order.
// ---------------------------------------------------------------------------
__global__ __launch_bounds__(256) void prep_rank_kernel(
    const float* __restrict__ means,
    const float* __restrict__ opac,
    const float* __restrict__ cols,
    const float* __restrict__ scales,
    const float* __restrict__ rots,
    const float* __restrict__ vm4,
    float* __restrict__ s,        // [NG][REC] sorted records
    float4* __restrict__ key4,    // [NG] sorted (mx,my,r2cull,0)
    float* __restrict__ radii_out)
{
    __shared__ __align__(16) float zl[NG];
    int tid = threadIdx.x;

    const double fx = 128.0, fy = 128.0;   // W/(2*tanfovx), H/(2*tanfovy)

    double R00 = vm4[0], R01 = vm4[1], R02 = vm4[2],  t0 = vm4[3];
    double R10 = vm4[4], R11 = vm4[5], R12 = vm4[6],  t1 = vm4[7];
    double R20 = vm4[8], R21 = vm4[9], R22 = vm4[10], t2 = vm4[11];

    // phase 1: all z-keys (identical in every block)
    for (int j = tid; j < NG; j += 256) {
        double zj = R20*means[3*j] + R21*means[3*j+1] + R22*means[3*j+2] + t2;
        zl[j] = (float)zj;
    }
    __syncthreads();

    // phase 2: exact stable rank (== jnp.argsort), 16 lanes per gaussian
    int g = tid >> 4;                 // gaussian-in-block 0..15
    int p = tid & 15;                 // part 0..15
    int i = blockIdx.x * 16 + g;
    float zi = zl[i];

    const float4* z4 = (const float4*)zl;
    int rank = 0;
    #pragma unroll 4
    for (int it = 0; it < 32; ++it) {
        int idx = it * 16 + p;        // interleaved float4 index
        float4 f = z4[idx];
        int j0 = idx * 4;
        rank += (f.x < zi) || (f.x == zi && (j0 + 0) < i);
        rank += (f.y < zi) || (f.y == zi && (j0 + 1) < i);
        rank += (f.z < zi) || (f.z == zi && (j0 + 2) < i);
        rank += (f.w < zi) || (f.w == zi && (j0 + 3) < i);
    }
    rank += __shfl_down(rank, 8, 16);
    rank += __shfl_down(rank, 4, 16);
    rank += __shfl_down(rank, 2, 16);
    rank += __shfl_down(rank, 1, 16);

    if (p != 0) return;

    // phase 3: full fp64 preprocess for gaussian i (one lane per gaussian)
    double m0 = means[3*i+0], m1 = means[3*i+1], m2 = means[3*i+2];
    double x = R00*m0 + R01*m1 + R02*m2 + t0;
    double y = R10*m0 + R11*m1 + R12*m2 + t1;
    double z = R20*m0 + R21*m1 + R22*m2 + t2;

    double zc   = fmax(z, 1e-4);
    double invz = 1.0 / zc;
    const double limx = 1.3 * 0.5, limy = 1.3 * 0.5;
    double tx = fmin(limx, fmax(-limx, x * invz)) * zc;
    double ty = fmin(limy, fmax(-limy, y * invz)) * zc;

    double J00 = fx * invz, J02 = -fx * tx * invz * invz;
    double J11 = fy * invz, J12 = -fy * ty * invz * invz;

    double qw = rots[4*i+0], qx = rots[4*i+1], qy = rots[4*i+2], qz = rots[4*i+3];
    double qn = 1.0 / sqrt(qw*qw + qx*qx + qy*qy + qz*qz);
    qw *= qn; qx *= qn; qy *= qn; qz *= qn;

    double Rg00 = 1.0 - 2.0*(qy*qy + qz*qz), Rg01 = 2.0*(qx*qy - qw*qz), Rg02 = 2.0*(qx*qz + qw*qy);
    double Rg10 = 2.0*(qx*qy + qw*qz), Rg11 = 1.0 - 2.0*(qx*qx + qz*qz), Rg12 = 2.0*(qy*qz - qw*qx);
    double Rg20 = 2.0*(qx*qz - qw*qy), Rg21 = 2.0*(qy*qz + qw*qx), Rg22 = 1.0 - 2.0*(qx*qx + qy*qy);

    double s0 = scales[3*i+0], s1 = scales[3*i+1], s2 = scales[3*i+2]; // SCALE_MOD = 1
    double M00 = Rg00*s0, M01 = Rg01*s1, M02 = Rg02*s2;
    double M10 = Rg10*s0, M11 = Rg11*s1, M12 = Rg12*s2;
    double M20 = Rg20*s0, M21 = Rg21*s1, M22 = Rg22*s2;

    double S00 = M00*M00 + M01*M01 + M02*M02;
    double S01 = M00*M10 + M01*M11 + M02*M12;
    double S02 = M00*M20 + M01*M21 + M02*M22;
    double S11 = M10*M10 + M11*M11 + M12*M12;
    double S12 = M10*M20 + M11*M21 + M12*M22;
    double S22 = M20*M20 + M21*M21 + M22*M22;

    double Ta0 = J00*R00 + J02*R20, Ta1 = J00*R01 + J02*R21, Ta2 = J00*R02 + J02*R22;
    double Tb0 = J11*R10 + J12*R20, Tb1 = J11*R11 + J12*R21, Tb2 = J11*R12 + J12*R22;

    double Ua0 = Ta0*S00 + Ta1*S01 + Ta2*S02;
    double Ua1 = Ta0*S01 + Ta1*S11 + Ta2*S12;
    double Ua2 = Ta0*S02 + Ta1*S12 + Ta2*S22;
    double Ub0 = Tb0*S00 + Tb1*S01 + Tb2*S02;
    double Ub1 = Tb0*S01 + Tb1*S11 + Tb2*S12;
    double Ub2 = Tb0*S02 + Tb1*S12 + Tb2*S22;
    double cov00 = Ua0*Ta0 + Ua1*Ta1 + Ua2*Ta2;
    double cov01 = Ua0*Tb0 + Ua1*Tb1 + Ua2*Tb2;
    double cov11 = Ub0*Tb0 + Ub1*Tb1 + Ub2*Tb2;

    double a = cov00 + 0.3;
    double b = cov01;
    double c = cov11 + 0.3;
    double det = a*c - b*b;
    bool valid = (det > 0.0) && (z > 0.2);
    double inv_det = (det != 0.0) ? (1.0 / det) : 0.0;
    double conA =  c * inv_det;
    double conB = -b * inv_det;
    double conC =  a * inv_det;
    double mid = 0.5 * (a + c);
    double lam = mid + sqrt(fmax(mid*mid - det, 0.1));
    float radii = valid ? (float)ceil(3.0 * sqrt(lam)) : 0.0f;

    double mx = fx * (x * invz) + 0.5 * (IMG_W - 1);
    double my = fy * (y * invz) + 0.5 * (IMG_H - 1);

    double op = valid ? (double)opac[i] : 0.0;

    // conservative cull radius^2: alpha>=1/255 => ||d||^2 <= 2*ln(255*op)*lam
    double r2c = -1.0;
    if (op > 0.0) {
        double lnterm = log(255.0 * op);
        if (lnterm > 0.0) r2c = 2.0 * lnterm * lam * 1.0001 + 1e-3;
    }

    float* dst = s + (size_t)rank * REC;
    *(float4*)(dst)     = make_float4((float)mx, (float)my, (float)conA, (float)conB);
    *(float4*)(dst + 4) = make_float4((float)conC, (float)op, (float)z, cols[3*i+0]);
    *(float4*)(dst + 8) = make_float4(cols[3*i+1], cols[3*i+2], (float)r2c, 0.0f);
    key4[rank]   = make_float4((float)mx, (float)my, (float)r2c, 0.0f);
    radii_out[i] = radii;
}

// ---------------------------------------------------------------------------
// Kernel B: per-tile compositing, 4 waves/tile, segment-parallel in depth.
// All 8 chunk cull-tests issued upfront (8 independent dwordx4 loads in
// flight); mask-0 chunks skipped without touching records; z/rgb shfls
// deferred behind an __any(take) gate. Segments combined exactly:
// color = sum_w c_w * prod_{w'<w} T_w'.
// ---------------------------------------------------------------------------
__global__ __launch_bounds__(256) void composite_kernel(
    const float* __restrict__ s,
    const float4* __restrict__ key4,
    const float* __restrict__ bg,
    float* __restrict__ out)
{
    __shared__ float comb[4 * 64 * 5];   // stride 5 -> no bank conflicts

    int tid  = threadIdx.x;
    int lane = tid & 63;
    int w    = tid >> 6;                 // segment/wave id 0..3
    int tile = blockIdx.x;
    int x0 = (tile & 15) * 8;
    int y0 = (tile >> 4) * 8;
    float x0f = (float)x0,       y0f = (float)y0;
    float x1f = (float)(x0 + 7), y1f = (float)(y0 + 7);

    int px = x0 + (lane & 7);
    int py = y0 + (lane >> 3);
    float fpx = (float)px, fpy = (float)py;
    int p = py * IMG_W + px;

    const int SEG = NG / 4;              // 512
    int segbase = w * SEG;

    // upfront cull: 8 chunks, loads all in flight before first use
    unsigned long long m[8];
    unsigned pb = 0;
    #pragma unroll
    for (int c = 0; c < 8; ++c) {
        float4 k4 = key4[segbase + c * 64 + lane];
        float ddx = fmaxf(0.f, fmaxf(x0f - k4.x, k4.x - x1f));
        float ddy = fmaxf(0.f, fmaxf(y0f - k4.y, k4.y - y1f));
        bool pass = (ddx*ddx + ddy*ddy) <= k4.z;
        m[c] = __ballot(pass);
        pb |= pass ? (1u << c) : 0u;
    }

    float cr = 0.f, cg = 0.f, cb = 0.f, dep = 0.f, T = 1.f;

    #pragma unroll
    for (int c = 0; c < 8; ++c) {
        unsigned long long mm = m[c];
        if (!mm) continue;
        float4 a0 = make_float4(0.f,0.f,0.f,0.f);
        float4 a1 = a0;
        float2 a2 = make_float2(0.f,0.f);
        if ((pb >> c) & 1u) {
            const float* r = s + (size_t)(segbase + c * 64 + lane) * REC;
            a0 = *(const float4*)(r);
            a1 = *(const float4*)(r + 4);
            a2 = *(const float2*)(r + 8);
        }
        while (mm) {
            int b = __ffsll(mm) - 1;     // lowest set bit = nearest depth
            mm &= mm - 1;
            float mx = __shfl(a0.x, b);
            float my = __shfl(a0.y, b);
            float A  = __shfl(a0.z, b);
            float B  = __shfl(a0.w, b);
            float C  = __shfl(a1.x, b);
            float op = __shfl(a1.y, b);
            float dx = mx - fpx;
            float dy = my - fpy;
            float power = -0.5f * (A*dx*dx + C*dy*dy) - B*dx*dy;
            float al = fminf(0.99f, op * __expf(power));
            bool take = (power <= 0.0f) && (al >= (1.0f / 255.0f));
            if (__any(take)) {
                float gz = __shfl(a1.z, b);
                float gr = __shfl(a1.w, b);
                float gg = __shfl(a2.x, b);
                float gb = __shfl(a2.y, b);
                float wgt = take ? al * T : 0.0f;
                dep += wgt * gz;
                cr  += wgt * gr;
                cg  += wgt * gg;
                cb  += wgt * gb;
                if (take) T *= (1.0f - al);
            }
        }
    }

    int cb_base = (w * 64 + lane) * 5;
    comb[cb_base + 0] = cr;
    comb[cb_base + 1] = cg;
    comb[cb_base + 2] = cb;
    comb[cb_base + 3] = dep;
    comb[cb_base + 4] = T;
    __syncthreads();

    if (w == 0) {
        float CR = 0.f, CG = 0.f, CB = 0.f, DEP = 0.f, TT = 1.f;
        #pragma unroll
        for (int ww = 0; ww < 4; ++ww) {
            int b2 = (ww * 64 + lane) * 5;
            CR  += TT * comb[b2 + 0];
            CG  += TT * comb[b2 + 1];
            CB  += TT * comb[b2 + 2];
            DEP += TT * comb[b2 + 3];
            TT  *= comb[b2 + 4];
        }
        out[0*NPIX + p] = CR + TT * bg[0];
        out[1*NPIX + p] = CG + TT * bg[1];
        out[2*NPIX + p] = CB + TT * bg[2];
        out[3*NPIX + NG + p]        = DEP;        // depth
        out[3*NPIX + NG + NPIX + p] = 1.f - TT;   // alpha image
    }
}

extern "C" void kernel_launch(void* const* d_in, const int* in_sizes, int n_in,
                              void* d_out, int out_size, void* d_ws, size_t ws_size,
                              hipStream_t stream)
{
    const float* means = (const float*)d_in[0];
    const float* opac  = (const float*)d_in[1];
    const float* cols  = (const float*)d_in[2];
    const float* scl   = (const float*)d_in[3];
    const float* rot   = (const float*)d_in[4];
    const float* vm    = (const float*)d_in[5];
    const float* bg    = (const float*)d_in[6];
    float* out = (float*)d_out;

    float*  s    = (float*)d_ws;          // NG*REC floats (sorted records)
    float4* key4 = (float4*)(s + NG * REC);

    prep_rank_kernel<<<NG / 16, 256, 0, stream>>>(
        means, opac, cols, scl, rot, vm, s, key4, out + 3 * NPIX);
    composite_kernel<<<NPIX / 64, 256, 0, stream>>>(s, key4, bg, out);
}